// Round 3
// baseline (586.810 us; speedup 1.0000x reference)
//
#include <hip/hip_runtime.h>
#include <math.h>

#define REGION_MAX 116
#define NREG 117
#define EMB 768
#define EMB4 192          // EMB/4 float4s per row
#define DIM_D 182
#define DIM_H 218
#define DIM_W 182
#define PPB 32            // points per scatter unit
#define BLOCK 256

// ws layout (int32 units):
//   [0..116]              per-region counts (atomics)
//   [128]                 nunits
//   [256 .. 256+MAXU)     unit descriptors: (chunk<<8)|region
//   [LIST_OFF + r*P + k]  per-region point lists
#define NUNITS_OFF 128
#define UNITS_OFF  256
#define LIST_OFF   8192

typedef float v4f __attribute__((ext_vector_type(4)));

__device__ __forceinline__ void compute_M(const float* __restrict__ mri,
                                          const float* __restrict__ aal,
                                          float* M /*LDS[12]*/) {
    // M = inv(aal) @ mri, top 3 rows. Gauss-Jordan w/ partial pivoting
    // (matches jnp.linalg.inv numerics; absmax==0 verified in prior rounds).
    float a[4][8];
    for (int i = 0; i < 4; ++i)
        for (int j = 0; j < 4; ++j) {
            a[i][j]     = aal[i * 4 + j];
            a[i][j + 4] = (i == j) ? 1.0f : 0.0f;
        }
    for (int c = 0; c < 4; ++c) {
        int piv = c;
        float best = fabsf(a[c][c]);
        for (int r = c + 1; r < 4; ++r) {
            float v = fabsf(a[r][c]);
            if (v > best) { best = v; piv = r; }
        }
        if (piv != c)
            for (int j = 0; j < 8; ++j) {
                float t = a[c][j]; a[c][j] = a[piv][j]; a[piv][j] = t;
            }
        float inv = 1.0f / a[c][c];
        for (int j = 0; j < 8; ++j) a[c][j] *= inv;
        for (int r = 0; r < 4; ++r) {
            if (r == c) continue;
            float f = a[r][c];
            for (int j = 0; j < 8; ++j) a[r][j] -= f * a[c][j];
        }
    }
    for (int i = 0; i < 3; ++i)
        for (int j = 0; j < 4; ++j) {
            float s = 0.0f;
            for (int k = 0; k < 4; ++k) s += a[i][4 + k] * mri[k * 4 + j];
            M[i * 4 + j] = s;
        }
}

__device__ __forceinline__ int region_of(const float* __restrict__ centers,
                                         const float* __restrict__ vol,
                                         const float* M, int p) {
    float px = centers[p * 3 + 0];
    float py = centers[p * 3 + 1];
    float pz = centers[p * 3 + 2];
    float fx = M[0] * px + M[1] * py + M[2]  * pz + M[3];
    float fy = M[4] * px + M[5] * py + M[6]  * pz + M[7];
    float fz = M[8] * px + M[9] * py + M[10] * pz + M[11];
    int x = (int)rintf(fx);   // round half-to-even, matches jnp.round
    int y = (int)rintf(fy);
    int z = (int)rintf(fz);
    bool inb = (x >= 0) & (x < DIM_D) & (y >= 0) & (y < DIM_H) &
               (z >= 0) & (z < DIM_W);
    int cx = min(max(x, 0), DIM_D - 1);
    int cy = min(max(y, 0), DIM_H - 1);
    int cz = min(max(z, 0), DIM_W - 1);
    int region = (int)vol[((size_t)cx * DIM_H + cy) * DIM_W + cz];
    return (inb && region >= 0 && region <= REGION_MAX) ? region : 0;
}

// --- K0: zero the region counters (ws is poisoned every iteration) ---
__global__ void k0_zero(int* __restrict__ ws) {
    if (threadIdx.x < NREG) ws[threadIdx.x] = 0;
}

// --- K1: region id per point + scatter point index into its region's list ---
__global__ __launch_bounds__(BLOCK) void k1_region(
    const float* __restrict__ centers, const float* __restrict__ mri,
    const float* __restrict__ aal, const float* __restrict__ vol,
    int* __restrict__ ws, int P) {
    __shared__ float M[12];
    if (threadIdx.x == 0) compute_M(mri, aal, M);
    __syncthreads();
    int p = blockIdx.x * blockDim.x + threadIdx.x;
    if (p >= P) return;
    int r = region_of(centers, vol, M, p);
    int slot = atomicAdd(&ws[r], 1);          // device-scope by default
    ws[LIST_OFF + r * P + slot] = p;
}

// --- K2: build unit list: one (region, chunk) descriptor per 32 points ---
__global__ void k2_units(int* __restrict__ ws) {
    __shared__ int sc[128];
    int t = threadIdx.x;                      // 128 threads
    int c = 0;
    if (t < NREG) c = (ws[t] + PPB - 1) / PPB;
    sc[t] = c;
    __syncthreads();
    for (int off = 1; off < 128; off <<= 1) { // Hillis-Steele inclusive scan
        int add = (t >= off) ? sc[t - off] : 0;
        __syncthreads();
        sc[t] += add;
        __syncthreads();
    }
    int start = sc[t] - c;
    if (t < NREG)
        for (int k = 0; k < c; ++k)
            ws[UNITS_OFF + start + k] = (k << 8) | t;
    if (t == 127) ws[NUNITS_OFF] = sc[127];
}

// --- K3: per unit, load the 3KB region row into LDS ONCE, then pure
// LDS->global streaming stores (structurally a fill: no global-load dep
// in the hot loop; table read traffic 201MB -> 6.5MB total). ---
__global__ __launch_bounds__(BLOCK) void k3_scatter(
    const int* __restrict__ ws, const float* __restrict__ table,
    float* __restrict__ out, int P) {
    __shared__ v4f row[EMB4];                 // 3 KB
    __shared__ int pid[PPB];
    const int nunits = ws[NUNITS_OFF];
    const v4f* __restrict__ tab4 = (const v4f*)table;
    for (int u = blockIdx.x; u < nunits; u += gridDim.x) {
        int e = ws[UNITS_OFF + u];
        int r = e & 255;
        int c = e >> 8;
        int base = c * PPB;
        int n = min(PPB, ws[r] - base);
        const int* __restrict__ lst = ws + LIST_OFF + r * P + base;
        __syncthreads();                      // protect LDS reuse across units
        if (threadIdx.x < EMB4) row[threadIdx.x] = tab4[r * EMB4 + threadIdx.x];
        if (threadIdx.x < n)    pid[threadIdx.x] = lst[threadIdx.x];
        __syncthreads();
        unsigned tot = (unsigned)n * EMB4;
        #pragma unroll 4
        for (unsigned j = threadIdx.x; j < tot; j += BLOCK) {
            unsigned pl = j / EMB4;           // 32-bit magic-mul
            unsigned c4 = j - pl * EMB4;
            v4f v = row[c4];
            __builtin_nontemporal_store(
                v, (v4f*)out + (unsigned)pid[pl] * EMB4 + c4);
        }
    }
}

// --- fallback (ws too small): R2 fused kernel, verified correct ---
__global__ __launch_bounds__(BLOCK) void fused_embed_kernel(
    const float* __restrict__ centers, const float* __restrict__ mri,
    const float* __restrict__ aal, const float* __restrict__ vol,
    const float* __restrict__ table, float* __restrict__ out, int P) {
    __shared__ float M[12];
    __shared__ int rids[PPB];
    if (threadIdx.x == 0) compute_M(mri, aal, M);
    __syncthreads();
    const int base = blockIdx.x * PPB;
    if (threadIdx.x < PPB) {
        const int p = base + threadIdx.x;
        rids[threadIdx.x] = (p < P) ? region_of(centers, vol, M, p) : 0;
    }
    __syncthreads();
    const int npts = min(PPB, P - base);
    const v4f* __restrict__ tab4 = (const v4f*)table;
    v4f* __restrict__ out4 = (v4f*)out + (long)base * EMB4;
    for (unsigned j = threadIdx.x; j < (unsigned)(npts * EMB4); j += BLOCK) {
        unsigned p = j / (unsigned)EMB4;
        unsigned c = j - p * (unsigned)EMB4;
        v4f v = tab4[(unsigned)rids[p] * (unsigned)EMB4 + c];
        __builtin_nontemporal_store(v, out4 + j);
    }
}

extern "C" void kernel_launch(void* const* d_in, const int* in_sizes, int n_in,
                              void* d_out, int out_size, void* d_ws, size_t ws_size,
                              hipStream_t stream) {
    const float* centers = (const float*)d_in[0];   // [B,N,3] f32
    const float* mri     = (const float*)d_in[1];   // [4,4]
    const float* aal     = (const float*)d_in[2];   // [4,4]
    const float* vol     = (const float*)d_in[3];   // [D,H,W]
    const float* table   = (const float*)d_in[4];   // [117,768]
    float* out = (float*)d_out;
    int*   ws  = (int*)d_ws;

    int P = in_sizes[0] / 3;                        // 65536
    size_t need = ((size_t)LIST_OFF + (size_t)NREG * (size_t)P) * sizeof(int);

    if (ws_size >= need) {
        int blocks1 = (P + BLOCK - 1) / BLOCK;      // 256
        int blocks3 = 2048;                         // 8 blocks/CU, grid-strides units
        k0_zero<<<1, 128, 0, stream>>>(ws);
        k1_region<<<blocks1, BLOCK, 0, stream>>>(centers, mri, aal, vol, ws, P);
        k2_units<<<1, 128, 0, stream>>>(ws);
        k3_scatter<<<blocks3, BLOCK, 0, stream>>>(ws, table, out, P);
    } else {
        int blocks = (P + PPB - 1) / PPB;           // 2048
        fused_embed_kernel<<<blocks, BLOCK, 0, stream>>>(
            centers, mri, aal, vol, table, out, P);
    }
}

// Round 4
// 222.184 us; speedup vs baseline: 2.6411x; 2.6411x over previous
//
#include <hip/hip_runtime.h>
#include <math.h>

#define REGION_MAX 116
#define EMB 768
#define EMB4 192          // EMB / 4 float4s per row
#define DIM_D 182
#define DIM_H 218
#define DIM_W 182
#define PPB 32            // points (output rows) per block
#define BLOCK 256

typedef float v4f __attribute__((ext_vector_type(4)));

// Fused kernel, identical to R2 EXCEPT: plain stores instead of
// __builtin_nontemporal_store. Single-variable A/B vs R2's 233.3 us.
// Theory: nt flag bypasses L2 write-combining -> 16B sub-line HBM writes
// -> RMW amplification caps stores at ~2.4 TB/s. Plain stores aggregate to
// full lines in L2 and evict at the fill kernel's proven 6.2 TB/s.
__global__ __launch_bounds__(BLOCK) void fused_embed_kernel(
    const float* __restrict__ centers,   // [P,3]
    const float* __restrict__ mri,       // [4,4]
    const float* __restrict__ aal,       // [4,4]
    const float* __restrict__ vol,       // [D,H,W]
    const float* __restrict__ table,     // [117, EMB]
    float* __restrict__ out,             // [P, EMB]
    int P) {
    __shared__ float M[12];
    __shared__ int rids[PPB];

    if (threadIdx.x == 0) {
        // M = inv(aal) @ mri, top 3 rows. Gauss-Jordan w/ partial pivoting
        // (matches jnp.linalg.inv numerics; absmax==0 across all rounds).
        float a[4][8];
        for (int i = 0; i < 4; ++i)
            for (int j = 0; j < 4; ++j) {
                a[i][j]     = aal[i * 4 + j];
                a[i][j + 4] = (i == j) ? 1.0f : 0.0f;
            }
        for (int c = 0; c < 4; ++c) {
            int piv = c;
            float best = fabsf(a[c][c]);
            for (int r = c + 1; r < 4; ++r) {
                float v = fabsf(a[r][c]);
                if (v > best) { best = v; piv = r; }
            }
            if (piv != c)
                for (int j = 0; j < 8; ++j) {
                    float t = a[c][j]; a[c][j] = a[piv][j]; a[piv][j] = t;
                }
            float inv = 1.0f / a[c][c];
            for (int j = 0; j < 8; ++j) a[c][j] *= inv;
            for (int r = 0; r < 4; ++r) {
                if (r == c) continue;
                float f = a[r][c];
                for (int j = 0; j < 8; ++j) a[r][j] -= f * a[c][j];
            }
        }
        for (int i = 0; i < 3; ++i)
            for (int j = 0; j < 4; ++j) {
                float s = 0.0f;
                for (int k = 0; k < 4; ++k) s += a[i][4 + k] * mri[k * 4 + j];
                M[i * 4 + j] = s;
            }
    }
    __syncthreads();

    const int base = blockIdx.x * PPB;

    // phase A: 32 threads compute region ids into LDS
    if (threadIdx.x < PPB) {
        const int p = base + threadIdx.x;
        int r = 0;
        if (p < P) {
            float px = centers[p * 3 + 0];
            float py = centers[p * 3 + 1];
            float pz = centers[p * 3 + 2];

            float fx = M[0] * px + M[1] * py + M[2]  * pz + M[3];
            float fy = M[4] * px + M[5] * py + M[6]  * pz + M[7];
            float fz = M[8] * px + M[9] * py + M[10] * pz + M[11];

            int x = (int)rintf(fx);   // round half-to-even, matches jnp.round
            int y = (int)rintf(fy);
            int z = (int)rintf(fz);

            bool inb = (x >= 0) & (x < DIM_D) & (y >= 0) & (y < DIM_H) &
                       (z >= 0) & (z < DIM_W);
            int cx = min(max(x, 0), DIM_D - 1);
            int cy = min(max(y, 0), DIM_H - 1);
            int cz = min(max(z, 0), DIM_W - 1);

            int region = (int)vol[((size_t)cx * DIM_H + cy) * DIM_W + cz];
            r = (inb && region >= 0 && region <= REGION_MAX) ? region : 0;
        }
        rids[threadIdx.x] = r;
    }
    __syncthreads();

    // phase B: stream PPB rows (contiguous 96 KB) of embeddings.
    // PLAIN stores (the only change vs R2): let L2 write-combine to full
    // lines before HBM eviction.
    const int npts = min(PPB, P - base);
    const v4f* __restrict__ tab4 = (const v4f*)table;
    v4f* __restrict__ out4 = (v4f*)out + (long)base * EMB4;

    if (npts == PPB) {
        #pragma unroll 4
        for (unsigned j = threadIdx.x; j < (unsigned)(PPB * EMB4); j += BLOCK) {
            unsigned p = j / (unsigned)EMB4;      // 32-bit magic-mul
            unsigned c = j - p * (unsigned)EMB4;
            out4[j] = tab4[(unsigned)rids[p] * (unsigned)EMB4 + c];
        }
    } else {
        for (unsigned j = threadIdx.x; j < (unsigned)(npts * EMB4); j += BLOCK) {
            unsigned p = j / (unsigned)EMB4;
            unsigned c = j - p * (unsigned)EMB4;
            out4[j] = tab4[(unsigned)rids[p] * (unsigned)EMB4 + c];
        }
    }
}

extern "C" void kernel_launch(void* const* d_in, const int* in_sizes, int n_in,
                              void* d_out, int out_size, void* d_ws, size_t ws_size,
                              hipStream_t stream) {
    const float* centers = (const float*)d_in[0];   // [B,N,3] f32
    const float* mri     = (const float*)d_in[1];   // [4,4]
    const float* aal     = (const float*)d_in[2];   // [4,4]
    const float* vol     = (const float*)d_in[3];   // [D,H,W]
    const float* table   = (const float*)d_in[4];   // [117,768]
    float* out = (float*)d_out;

    int P = in_sizes[0] / 3;                        // 65536
    int blocks = (P + PPB - 1) / PPB;               // 2048
    fused_embed_kernel<<<blocks, BLOCK, 0, stream>>>(
        centers, mri, aal, vol, table, out, P);
}